// Round 2
// baseline (577.018 us; speedup 1.0000x reference)
//
#include <hip/hip_runtime.h>

#define ZD 510
#define NK 128

// --- c_sq[k] = sum_d codebook[k][d]^2, accumulated in fp64 for accuracy ---
__global__ void csq_kernel(const float* __restrict__ cb, float* __restrict__ csq) {
    int k = threadIdx.x;
    if (k >= NK) return;
    const float* row = cb + (size_t)k * ZD;
    double s = 0.0;
    for (int d = 0; d < ZD; ++d) {
        double v = (double)row[d];
        s = fma(v, v, s);
    }
    csq[k] = (float)s;
}

// Fused: cross = z @ cb^T (128x128 block tile, 8x8/thread), score = c_sq - 2*cross,
// argmin over K, gather codebook[kmin] to out.
__global__ __launch_bounds__(256, 4) void vq_kernel(
    const float* __restrict__ z, const float* __restrict__ cb,
    const float* __restrict__ csq, float* __restrict__ out) {
    // transposed tiles [d][row], stride 132 to keep staging writes mild (4-way max)
    __shared__ __align__(16) float zs[32][132];
    __shared__ __align__(16) float cs[32][132];
    __shared__ int kmin_s[128];

    const int tid  = threadIdx.x;
    const int row0 = blockIdx.x << 7;          // 128 rows per block
    const int tr   = tid >> 4;                 // 0..15 -> row group
    const int tc   = tid & 15;                 // 0..15 -> col group

    float acc[8][8];
#pragma unroll
    for (int i = 0; i < 8; ++i)
#pragma unroll
        for (int j = 0; j < 8; ++j) acc[i][j] = 0.f;

    for (int t = 0; t < 16; ++t) {             // 16 tiles of 32 d (510 padded to 512)
        const int d0 = t << 5;
        // stage: 128 rows x 32 d, float2 global loads (rows only 8B-aligned), zero-pad d>=510
#pragma unroll
        for (int i = 0; i < 8; ++i) {
            int li = tid + (i << 8);           // 0..2047 float2-slots
            int r  = li >> 4;                  // 16 float2 per row
            int dl = (li & 15) << 1;
            int d  = d0 + dl;
            float2 zv = make_float2(0.f, 0.f), cv = make_float2(0.f, 0.f);
            if (d < ZD) {
                zv = *(const float2*)(z  + (size_t)(row0 + r) * ZD + d);
                cv = *(const float2*)(cb + (size_t)r * ZD + d);
            }
            zs[dl][r] = zv.x; zs[dl + 1][r] = zv.y;
            cs[dl][r] = cv.x; cs[dl + 1][r] = cv.y;
        }
        __syncthreads();
#pragma unroll 8
        for (int dl = 0; dl < 32; ++dl) {
            float4 a0 = *(const float4*)&zs[dl][tr << 2];
            float4 a1 = *(const float4*)&zs[dl][64 + (tr << 2)];
            float4 b0 = *(const float4*)&cs[dl][tc << 2];
            float4 b1 = *(const float4*)&cs[dl][64 + (tc << 2)];
            float a[8] = {a0.x, a0.y, a0.z, a0.w, a1.x, a1.y, a1.z, a1.w};
            float b[8] = {b0.x, b0.y, b0.z, b0.w, b1.x, b1.y, b1.z, b1.w};
#pragma unroll
            for (int i = 0; i < 8; ++i)
#pragma unroll
                for (int j = 0; j < 8; ++j)
                    acc[i][j] = fmaf(a[i], b[j], acc[i][j]);
        }
        __syncthreads();
    }

    // ---- epilogue: score = c_sq - 2*cross, per-row argmin ----
    float q[8];
    {
        int c0 = tc << 2, c1 = 64 + (tc << 2);
#pragma unroll
        for (int j = 0; j < 4; ++j) { q[j] = csq[c0 + j]; q[4 + j] = csq[c1 + j]; }
    }
#pragma unroll
    for (int i = 0; i < 8; ++i) {
        float bv = fmaf(-2.f, acc[i][0], q[0]);
        int   bk = tc << 2;
#pragma unroll
        for (int j = 1; j < 8; ++j) {
            float v  = fmaf(-2.f, acc[i][j], q[j]);
            int   kk = (j < 4) ? (tc << 2) + j : 64 + (tc << 2) + (j - 4);
            if (v < bv || (v == bv && kk < bk)) { bv = v; bk = kk; }
        }
        // reduce across the 16 lanes (tc) sharing this row; lower index wins ties
#pragma unroll
        for (int m = 1; m <= 8; m <<= 1) {
            float ov = __shfl_xor(bv, m, 64);
            int   ok = __shfl_xor(bk, m, 64);
            if (ov < bv || (ov == bv && ok < bk)) { bv = ov; bk = ok; }
        }
        if (tc == 0) {
            int row = (i < 4) ? (tr << 2) + i : 64 + (tr << 2) + (i - 4);
            kmin_s[row] = bk;
        }
    }
    __syncthreads();

    // ---- gather write: 2 rows/pass, 128 threads/row, float2 (rows are 8B-aligned) ----
    const int half = tid >> 7;   // 0/1
    const int h    = tid & 127;
    for (int rp = 0; rp < 64; ++rp) {
        int row = (rp << 1) + half;
        int k   = kmin_s[row];
        const float2* src = (const float2*)(cb + (size_t)k * ZD);
        float2*       dst = (float2*)(out + (size_t)(row0 + row) * ZD);
        dst[h] = src[h];
        if (h < 127) dst[128 + h] = src[128 + h];   // 255 float2 = 510 floats
    }
}

extern "C" void kernel_launch(void* const* d_in, const int* in_sizes, int n_in,
                              void* d_out, int out_size, void* d_ws, size_t ws_size,
                              hipStream_t stream) {
    const float* z  = (const float*)d_in[0];
    const float* cb = (const float*)d_in[1];
    float* out = (float*)d_out;
    float* csq = (float*)d_ws;
    hipLaunchKernelGGL(csq_kernel, dim3(1), dim3(128), 0, stream, cb, csq);
    hipLaunchKernelGGL(vq_kernel, dim3(2048), dim3(256), 0, stream, z, cb, csq, out);
}